// Round 4
// baseline (18007.733 us; speedup 1.0000x reference)
//
#include <hip/hip_runtime.h>
#include <hip/hip_cooperative_groups.h>
#include <cstdint>

namespace cg = cooperative_groups;

constexpr int BB = 128;   // batch
constexpr int SS = 512;   // source length
constexpr int DD = 512;   // hidden dim
constexpr int TT = 64;    // decode steps
constexpr int OO = 3;     // output dim

__device__ __forceinline__ float tanh_fast(float x) {
  float e = __expf(2.0f * x);
  return 1.0f - 2.0f / (e + 1.0f);
}
__device__ __forceinline__ float sigmoid_fast(float x) {
  return 1.0f / (1.0f + __expf(-x));
}
__device__ __forceinline__ unsigned short f2bf(float f) {
  uint32_t u = __float_as_uint(f);
  uint32_t r = (u + 0x7FFFu + ((u >> 16) & 1u)) >> 16;  // RNE
  return (unsigned short)r;
}
__device__ __forceinline__ float2 bfx2(uint32_t u) {
  float2 r;
  r.x = __uint_as_float(u << 16);
  r.y = __uint_as_float(u & 0xFFFF0000u);
  return r;
}

// ---------------------------------------------------------------------------
// Uk = e_all(view [B*S, D]) @ Ua^T + bu -> bf16 [B*S, D]   (fp32 vector GEMM)
// ---------------------------------------------------------------------------
__global__ __launch_bounds__(256) void gemm_uk(
    const float* __restrict__ A, const float* __restrict__ Bw,
    const float* __restrict__ bias, unsigned short* __restrict__ Uk) {
  constexpr int BM = 128, BN = 128, BK = 16, TM = 8, TN = 8, TX = 16;
  __shared__ float As[BK][BM + 4];
  __shared__ float Bs[BK][BN + 4];
  const int tid = threadIdx.x;
  const int bm = blockIdx.y * BM, bn = blockIdx.x * BN;
  const int tx = tid % TX, ty = tid / TX;
  float acc[TM][TN];
#pragma unroll
  for (int i = 0; i < TM; ++i)
#pragma unroll
    for (int j = 0; j < TN; ++j) acc[i][j] = 0.f;

  for (int k0 = 0; k0 < DD; k0 += BK) {
#pragma unroll
    for (int i = 0; i < BM * BK / 256; ++i) {
      int idx = tid + i * 256;
      int m = idx / BK, k = idx % BK;
      As[k][m] = A[(size_t)(bm + m) * DD + k0 + k];
    }
#pragma unroll
    for (int i = 0; i < BN * BK / 256; ++i) {
      int idx = tid + i * 256;
      int n = idx / BK, k = idx % BK;
      Bs[k][n] = Bw[(size_t)(bn + n) * DD + k0 + k];
    }
    __syncthreads();
#pragma unroll
    for (int k = 0; k < BK; ++k) {
      float ra[TM], rb[TN];
#pragma unroll
      for (int i = 0; i < TM; ++i) ra[i] = As[k][ty * TM + i];
#pragma unroll
      for (int j = 0; j < TN; ++j) rb[j] = Bs[k][tx * TN + j];
#pragma unroll
      for (int i = 0; i < TM; ++i)
#pragma unroll
        for (int j = 0; j < TN; ++j) acc[i][j] += ra[i] * rb[j];
    }
    __syncthreads();
  }
#pragma unroll
  for (int i = 0; i < TM; ++i) {
    int m = bm + ty * TM + i;
    uint32_t* row = (uint32_t*)(Uk + (size_t)m * DD + bn + tx * TN);
#pragma unroll
    for (int j = 0; j < TN / 2; ++j) {
      int n = bn + tx * TN + 2 * j;
      uint32_t lo = f2bf(acc[i][2 * j] + bias[n]);
      uint32_t hi = f2bf(acc[i][2 * j + 1] + bias[n + 1]);
      row[j] = lo | (hi << 16);
    }
  }
}

// WaT_bf[d, e] = bf16(Wa[e, d])
__global__ void transp_wa_bf(const float* __restrict__ Wa,
                             unsigned short* __restrict__ WaT) {
  int idx = blockIdx.x * 256 + threadIdx.x;  // e*512+d
  int e = idx >> 9, d = idx & (DD - 1);
  WaT[(size_t)d * DD + e] = f2bf(Wa[idx]);
}

// fp32 -> bf16, 8 elems/thread
__global__ __launch_bounds__(256) void conv_e(const float* __restrict__ in,
                                              unsigned short* __restrict__ outp) {
  size_t idx = ((size_t)blockIdx.x * 256 + threadIdx.x) * 8;
  const float4* p = (const float4*)(in + idx);
  float4 a = p[0], b = p[1];
  uint4 r;
  r.x = f2bf(a.x) | ((uint32_t)f2bf(a.y) << 16);
  r.y = f2bf(a.z) | ((uint32_t)f2bf(a.w) << 16);
  r.z = f2bf(b.x) | ((uint32_t)f2bf(b.y) << 16);
  r.w = f2bf(b.z) | ((uint32_t)f2bf(b.w) << 16);
  *(uint4*)(outp + idx) = r;
}

// ---------------------------------------------------------------------------
// Persistent cooperative decoder: all 64 steps, 4 phases/step + grid.sync.
// Grid MUST be 256 blocks x 1024 threads (1 block/CU).
// ---------------------------------------------------------------------------
__global__ __launch_bounds__(1024, 4) void decoder_persistent(
    const unsigned short* __restrict__ Uk_bf,
    const unsigned short* __restrict__ e_bf,
    const float* __restrict__ e_last,
    const float* __restrict__ target,
    const unsigned short* __restrict__ WaT_bf,
    const float* __restrict__ ba,
    const float* __restrict__ va,
    const float* __restrict__ vb_p,
    const float* __restrict__ W_ih,
    const float* __restrict__ b_ih,
    const float* __restrict__ W_hh,
    const float* __restrict__ b_hh,
    const float* __restrict__ W_out,
    const float* __restrict__ b_out,
    float* __restrict__ scores,
    float* __restrict__ q,
    float* __restrict__ h,
    float* __restrict__ ctx,
    float* __restrict__ gi,
    float* __restrict__ gh,
    float* __restrict__ out_d,
    float* __restrict__ out_hT,
    float* __restrict__ out_attn) {
  cg::grid_group gg = cg::this_grid();
  const int bid = blockIdx.x;
  const int tid = threadIdx.x;

  __shared__ union SM {
    struct { float4 q[128]; float4 va[128]; } a;
    struct { float w[512]; float red[16]; float2 part[8][128]; } b;
    struct { float A[128][68]; float W[16][68]; } c;   // +4 pad: kills 8-way conflict
    struct { float hn[512]; float2 qp[4][256]; } d;
  } sm;

  const int wid = tid >> 6, lane = tid & 63;

  // ---- init: h = e_last ; q = h @ Wa^T + ba
  if (bid < BB) {
    const int b = bid;
    if (tid < DD) {
      float hv = e_last[(size_t)b * DD + tid];
      h[(size_t)b * DD + tid] = hv;
      sm.d.hn[tid] = hv;
    }
    __syncthreads();
    {
      const int e2 = tid & 255, kh = tid >> 8;
      const uint32_t* W32 = (const uint32_t*)WaT_bf;
      float2 acc = {0.f, 0.f};
      for (int dd = kh * 128; dd < kh * 128 + 128; ++dd) {
        float2 wv = bfx2(W32[(size_t)dd * 256 + e2]);
        float hv = sm.d.hn[dd];
        acc.x += hv * wv.x;
        acc.y += hv * wv.y;
      }
      sm.d.qp[kh][e2] = acc;
      __syncthreads();
      if (tid < 256) {
        float2 r0 = sm.d.qp[0][tid], r1 = sm.d.qp[1][tid];
        float2 r2 = sm.d.qp[2][tid], r3 = sm.d.qp[3][tid];
        q[(size_t)b * DD + 2 * tid] = r0.x + r1.x + r2.x + r3.x + ba[2 * tid];
        q[(size_t)b * DD + 2 * tid + 1] = r0.y + r1.y + r2.y + r3.y + ba[2 * tid + 1];
      }
    }
  }
  gg.sync();

  for (int t = 0; t < TT; ++t) {
    // ================= phase A: scores[b,s] = va . tanh(q+Uk) + vb ========
    {
      const int b = bid >> 1, shalf = bid & 1;
      if (tid < 128) {
        sm.a.q[tid] = ((const float4*)(q + (size_t)b * DD))[tid];
        sm.a.va[tid] = ((const float4*)va)[tid];
      }
      __syncthreads();
      const float vb = vb_p[0];
      const int g = tid >> 4, l = tid & 15;
#pragma unroll
      for (int i = 0; i < 4; ++i) {
        const int s = shalf * 256 + g + 64 * i;
        const uint2* row = (const uint2*)(Uk_bf + ((size_t)b * SS + s) * DD);
        float acc = 0.f;
#pragma unroll
        for (int j = 0; j < 8; ++j) {
          uint2 u = row[l + 16 * j];
          float4 qq = sm.a.q[l + 16 * j];
          float4 vv = sm.a.va[l + 16 * j];
          float2 e0 = bfx2(u.x), e1 = bfx2(u.y);
          acc += vv.x * tanh_fast(qq.x + e0.x);
          acc += vv.y * tanh_fast(qq.y + e0.y);
          acc += vv.z * tanh_fast(qq.z + e1.x);
          acc += vv.w * tanh_fast(qq.w + e1.y);
        }
#pragma unroll
        for (int off = 8; off; off >>= 1) acc += __shfl_down(acc, off, 16);
        if (l == 0) scores[(size_t)b * SS + s] = acc + vb;
      }
    }
    gg.sync();

    // ================= phase B: softmax + ctx ============================
    {
      const int b = bid >> 1, dhalf = bid & 1;
      float v = (tid < 512) ? scores[(size_t)b * SS + tid] : -3.4e38f;
      float m = v;
#pragma unroll
      for (int off = 32; off; off >>= 1) m = fmaxf(m, __shfl_xor(m, off));
      if (lane == 0) sm.b.red[wid] = m;
      __syncthreads();
      if (tid < 16) {
        float mm = sm.b.red[tid];
#pragma unroll
        for (int off = 8; off; off >>= 1) mm = fmaxf(mm, __shfl_xor(mm, off, 16));
        sm.b.red[tid] = mm;
      }
      __syncthreads();
      m = sm.b.red[0];
      float e_ = (tid < 512) ? __expf(v - m) : 0.f;
      float ssum = e_;
#pragma unroll
      for (int off = 32; off; off >>= 1) ssum += __shfl_xor(ssum, off);
      __syncthreads();
      if (lane == 0) sm.b.red[wid] = ssum;
      __syncthreads();
      if (tid < 16) {
        float s2 = sm.b.red[tid];
#pragma unroll
        for (int off = 8; off; off >>= 1) s2 += __shfl_xor(s2, off, 16);
        sm.b.red[tid] = s2;
      }
      __syncthreads();
      const float inv = 1.f / sm.b.red[0];
      if (tid < 512) {
        float wv = e_ * inv;
        sm.b.w[tid] = wv;
        if (dhalf == 0) out_attn[((size_t)b * TT + t) * SS + tid] = wv;
      }
      __syncthreads();

      const int cp = tid & 127, sg = tid >> 7;
      const uint32_t* e32 = (const uint32_t*)e_bf;
      const size_t base = (size_t)b * SS * (DD / 2) + dhalf * 128 + cp;
      float2 acc = {0.f, 0.f};
      for (int s = sg * 64; s < sg * 64 + 64; ++s) {
        float2 ev = bfx2(e32[base + (size_t)s * (DD / 2)]);
        float ws = sm.b.w[s];
        acc.x += ws * ev.x;
        acc.y += ws * ev.y;
      }
      sm.b.part[sg][cp] = acc;
      __syncthreads();
      if (tid < 128) {
        float2 r = {0.f, 0.f};
#pragma unroll
        for (int k = 0; k < 8; ++k) {
          r.x += sm.b.part[k][tid].x;
          r.y += sm.b.part[k][tid].y;
        }
        ((float2*)(ctx + (size_t)b * DD + dhalf * 256))[tid] = r;
      }
    }
    gg.sync();

    // ================= phase C: gates GEMM (weight-stationary) ===========
    // blocks 0..95: gi = ctx @ W_ih[:, :512]^T + b_ih  (ld 515)
    // blocks 96..191: gh = h @ W_hh^T + b_hh
    if (bid < 192) {
      const bool isI = bid < 96;
      const float* Asrc = isI ? ctx : h;
      const float* Wsrc = isI ? W_ih : W_hh;
      const int ldw = isI ? (DD + OO) : DD;
      const float* bias = isI ? b_ih : b_hh;
      float* dst = isI ? gi : gh;
      const int c0 = (isI ? bid : bid - 96) * 16;
      const int r = tid >> 3, c = tid & 7;
      float acc1 = 0.f, acc2 = 0.f;
      for (int k0 = 0; k0 < DD; k0 += 64) {
        {
          const float4* src = (const float4*)(Asrc + (size_t)r * DD + k0 + c * 8);
          float4 a0 = src[0], a1 = src[1];
          *(float4*)&sm.c.A[r][c * 8] = a0;
          *(float4*)&sm.c.A[r][c * 8 + 4] = a1;
        }
        {
          int wr = tid >> 6, wk = tid & 63;
          sm.c.W[wr][wk] = Wsrc[(size_t)(c0 + wr) * ldw + k0 + wk];
        }
        __syncthreads();
#pragma unroll
        for (int kk = 0; kk < 64; ++kk) {
          float a = sm.c.A[r][kk];
          acc1 += a * sm.c.W[c][kk];
          acc2 += a * sm.c.W[c + 8][kk];
        }
        __syncthreads();
      }
      const int j1 = c0 + c, j2 = c0 + c + 8;
      dst[(size_t)r * 3 * DD + j1] = acc1 + bias[j1];
      dst[(size_t)r * 3 * DD + j2] = acc2 + bias[j2];
    }
    gg.sync();

    // ================= phase D: GRU pointwise + out-proj + q_next ========
    if (bid < BB) {
      const int b = bid;
      if (tid < DD) {
        const int d = tid;
        float x0 = 0.f, x1 = 0.f, x2 = 0.f;
        if (t > 0) {
          const float* xp = target + ((size_t)b * TT + (t - 1)) * OO;
          x0 = xp[0]; x1 = xp[1]; x2 = xp[2];
        }
        const float* gib = gi + (size_t)b * 3 * DD;
        const float* ghb = gh + (size_t)b * 3 * DD;
        const float* w0 = W_ih + (size_t)d * (DD + OO) + DD;
        const float* w1 = W_ih + (size_t)(DD + d) * (DD + OO) + DD;
        const float* w2 = W_ih + (size_t)(2 * DD + d) * (DD + OO) + DD;
        float ir = gib[d] + x0 * w0[0] + x1 * w0[1] + x2 * w0[2];
        float iz = gib[DD + d] + x0 * w1[0] + x1 * w1[1] + x2 * w1[2];
        float in_ = gib[2 * DD + d] + x0 * w2[0] + x1 * w2[1] + x2 * w2[2];
        float rg = sigmoid_fast(ir + ghb[d]);
        float z = sigmoid_fast(iz + ghb[DD + d]);
        float n = tanh_fast(in_ + rg * ghb[2 * DD + d]);
        float hp = h[(size_t)b * DD + d];
        float hnew = (1.f - z) * n + z * hp;
        h[(size_t)b * DD + d] = hnew;
        sm.d.hn[d] = hnew;
        if (t == TT - 1) out_hT[(size_t)b * DD + d] = hnew;
      }
      __syncthreads();
      // out[b,t,o]
      if (wid < OO) {
        const float* wrow = W_out + (size_t)wid * DD;
        float acc = 0.f;
        for (int i = lane; i < DD; i += 64) acc += sm.d.hn[i] * wrow[i];
#pragma unroll
        for (int off = 32; off; off >>= 1) acc += __shfl_xor(acc, off);
        if (lane == 0) out_d[((size_t)b * TT + t) * OO + wid] = acc + b_out[wid];
      }
      // q_next = hn @ Wa^T + ba
      {
        const int e2 = tid & 255, kh = tid >> 8;
        const uint32_t* W32 = (const uint32_t*)WaT_bf;
        float2 acc = {0.f, 0.f};
        for (int dd = kh * 128; dd < kh * 128 + 128; ++dd) {
          float2 wv = bfx2(W32[(size_t)dd * 256 + e2]);
          float hv = sm.d.hn[dd];
          acc.x += hv * wv.x;
          acc.y += hv * wv.y;
        }
        sm.d.qp[kh][e2] = acc;
        __syncthreads();
        if (tid < 256) {
          float2 r0 = sm.d.qp[0][tid], r1 = sm.d.qp[1][tid];
          float2 r2 = sm.d.qp[2][tid], r3 = sm.d.qp[3][tid];
          q[(size_t)b * DD + 2 * tid] = r0.x + r1.x + r2.x + r3.x + ba[2 * tid];
          q[(size_t)b * DD + 2 * tid + 1] = r0.y + r1.y + r2.y + r3.y + ba[2 * tid + 1];
        }
      }
    }
    gg.sync();
  }
}

// ---------------------------------------------------------------------------
extern "C" void kernel_launch(void* const* d_in, const int* in_sizes, int n_in,
                              void* d_out, int out_size, void* d_ws, size_t ws_size,
                              hipStream_t stream) {
  const float* e_all  = (const float*)d_in[0];
  const float* e_last = (const float*)d_in[1];
  const float* target = (const float*)d_in[2];
  const float* Wa     = (const float*)d_in[3];
  const float* ba     = (const float*)d_in[4];
  const float* Ua     = (const float*)d_in[5];
  const float* bu     = (const float*)d_in[6];
  const float* Va_w   = (const float*)d_in[7];
  const float* Va_b   = (const float*)d_in[8];
  const float* W_ih   = (const float*)d_in[9];
  const float* b_ih   = (const float*)d_in[10];
  const float* W_hh   = (const float*)d_in[11];
  const float* b_hh   = (const float*)d_in[12];
  const float* W_out  = (const float*)d_in[13];
  const float* b_out  = (const float*)d_in[14];

  float* out      = (float*)d_out;
  float* out_d    = out;                         // [B,T,3]
  float* out_hT   = out + (size_t)BB * TT * OO;  // [1,B,D]
  float* out_attn = out_hT + (size_t)BB * DD;    // [B,T,S]

  // Workspace: 137.36 MB total (proven-safe bound: 139.48 MB passed in R1).
  char* wsB = (char*)d_ws;
  unsigned short* Uk_bf = (unsigned short*)wsB;                       // 67.11 MB
  unsigned short* e_bf  = (unsigned short*)(wsB + (size_t)BB * SS * DD * 2);  // 67.11 MB
  unsigned short* WaT_bf = (unsigned short*)(wsB + (size_t)BB * SS * DD * 4); // 0.52 MB
  float* fws = (float*)(wsB + (size_t)BB * SS * DD * 4 + (size_t)DD * DD * 2);
  float* scores = fws;                            // B*S
  float* q   = scores + (size_t)BB * SS;          // B*D
  float* h   = q + (size_t)BB * DD;               // B*D
  float* ctx = h + (size_t)BB * DD;               // B*D
  float* gi  = ctx + (size_t)BB * DD;             // B*3D
  float* gh  = gi + (size_t)BB * 3 * DD;          // B*3D

  transp_wa_bf<<<(DD * DD) / 256, 256, 0, stream>>>(Wa, WaT_bf);
  conv_e<<<(BB * SS * DD) / (8 * 256), 256, 0, stream>>>(e_all, e_bf);
  gemm_uk<<<dim3(DD / 128, (BB * SS) / 128), 256, 0, stream>>>(e_all, Ua, bu, Uk_bf);

  void* args[] = {
      (void*)&Uk_bf, (void*)&e_bf, (void*)&e_last, (void*)&target,
      (void*)&WaT_bf, (void*)&ba, (void*)&Va_w, (void*)&Va_b,
      (void*)&W_ih, (void*)&b_ih, (void*)&W_hh, (void*)&b_hh,
      (void*)&W_out, (void*)&b_out,
      (void*)&scores, (void*)&q, (void*)&h, (void*)&ctx,
      (void*)&gi, (void*)&gh,
      (void*)&out_d, (void*)&out_hT, (void*)&out_attn};
  hipLaunchCooperativeKernel((void*)decoder_persistent, dim3(256), dim3(1024),
                             args, 0, stream);
}

// Round 5
// 7025.358 us; speedup vs baseline: 2.5632x; 2.5632x over previous
//
#include <hip/hip_runtime.h>
#include <cstdint>

constexpr int BB = 128;   // batch
constexpr int SS = 512;   // source length
constexpr int DD = 512;   // hidden dim
constexpr int TT = 64;    // decode steps
constexpr int OO = 3;     // output dim

__device__ __forceinline__ float tanh_fast(float x) {
  float e = __expf(2.0f * x);
  return 1.0f - 2.0f / (e + 1.0f);
}
__device__ __forceinline__ float sigmoid_fast(float x) {
  return 1.0f / (1.0f + __expf(-x));
}
__device__ __forceinline__ unsigned short f2bf(float f) {
  uint32_t u = __float_as_uint(f);
  uint32_t r = (u + 0x7FFFu + ((u >> 16) & 1u)) >> 16;  // RNE
  return (unsigned short)r;
}
__device__ __forceinline__ float bf2f(unsigned short s) {
  return __uint_as_float((uint32_t)s << 16);
}
__device__ __forceinline__ float2 bfx2(uint32_t u) {
  float2 r;
  r.x = __uint_as_float(u << 16);
  r.y = __uint_as_float(u & 0xFFFF0000u);
  return r;
}

// ---------------------------------------------------------------------------
// Generic tiled fp32 GEMM body: C[m,n] = sum_k A[m,k] * Bw[n,k] + bias[n]
// ---------------------------------------------------------------------------
template<int BM, int BN, int BK, int TM, int TN>
__device__ __forceinline__ void gemm_body(
    const float* __restrict__ A, int lda,
    const float* __restrict__ Bw, int ldb,
    const float* __restrict__ bias,
    float* __restrict__ C, int ldc, int K) {
  constexpr int TX = BN / TN, TY = BM / TM;
  static_assert(TX * TY == 256, "tile/thread mismatch");
  __shared__ float As[BK][BM + 4];
  __shared__ float Bs[BK][BN + 4];
  const int tid = threadIdx.x;
  const int bm = blockIdx.y * BM, bn = blockIdx.x * BN;
  const int tx = tid % TX, ty = tid / TX;
  float acc[TM][TN];
#pragma unroll
  for (int i = 0; i < TM; ++i)
#pragma unroll
    for (int j = 0; j < TN; ++j) acc[i][j] = 0.f;

  for (int k0 = 0; k0 < K; k0 += BK) {
#pragma unroll
    for (int i = 0; i < BM * BK / 256; ++i) {
      int idx = tid + i * 256;
      int m = idx / BK, k = idx % BK;
      As[k][m] = A[(size_t)(bm + m) * lda + k0 + k];
    }
#pragma unroll
    for (int i = 0; i < BN * BK / 256; ++i) {
      int idx = tid + i * 256;
      int n = idx / BK, k = idx % BK;
      Bs[k][n] = Bw[(size_t)(bn + n) * ldb + k0 + k];
    }
    __syncthreads();
#pragma unroll
    for (int k = 0; k < BK; ++k) {
      float ra[TM], rb[TN];
#pragma unroll
      for (int i = 0; i < TM; ++i) ra[i] = As[k][ty * TM + i];
#pragma unroll
      for (int j = 0; j < TN; ++j) rb[j] = Bs[k][tx * TN + j];
#pragma unroll
      for (int i = 0; i < TM; ++i)
#pragma unroll
        for (int j = 0; j < TN; ++j) acc[i][j] += ra[i] * rb[j];
    }
    __syncthreads();
  }
#pragma unroll
  for (int i = 0; i < TM; ++i) {
    int m = bm + ty * TM + i;
#pragma unroll
    for (int j = 0; j < TN; ++j) {
      int n = bn + tx * TN + j;
      C[(size_t)m * ldc + n] = acc[i][j] + bias[n];
    }
  }
}

// Uk = e_all(view [B*S, D]) @ Ua^T + bu -> bf16 [B*S, D]
__global__ __launch_bounds__(256) void gemm_uk(
    const float* __restrict__ A, const float* __restrict__ Bw,
    const float* __restrict__ bias, unsigned short* __restrict__ Uk) {
  constexpr int BM = 128, BN = 128, BK = 16, TM = 8, TN = 8, TX = 16;
  __shared__ float As[BK][BM + 4];
  __shared__ float Bs[BK][BN + 4];
  const int tid = threadIdx.x;
  const int bm = blockIdx.y * BM, bn = blockIdx.x * BN;
  const int tx = tid % TX, ty = tid / TX;
  float acc[TM][TN];
#pragma unroll
  for (int i = 0; i < TM; ++i)
#pragma unroll
    for (int j = 0; j < TN; ++j) acc[i][j] = 0.f;

  for (int k0 = 0; k0 < DD; k0 += BK) {
#pragma unroll
    for (int i = 0; i < BM * BK / 256; ++i) {
      int idx = tid + i * 256;
      int m = idx / BK, k = idx % BK;
      As[k][m] = A[(size_t)(bm + m) * DD + k0 + k];
    }
#pragma unroll
    for (int i = 0; i < BN * BK / 256; ++i) {
      int idx = tid + i * 256;
      int n = idx / BK, k = idx % BK;
      Bs[k][n] = Bw[(size_t)(bn + n) * DD + k0 + k];
    }
    __syncthreads();
#pragma unroll
    for (int k = 0; k < BK; ++k) {
      float ra[TM], rb[TN];
#pragma unroll
      for (int i = 0; i < TM; ++i) ra[i] = As[k][ty * TM + i];
#pragma unroll
      for (int j = 0; j < TN; ++j) rb[j] = Bs[k][tx * TN + j];
#pragma unroll
      for (int i = 0; i < TM; ++i)
#pragma unroll
        for (int j = 0; j < TN; ++j) acc[i][j] += ra[i] * rb[j];
    }
    __syncthreads();
  }
#pragma unroll
  for (int i = 0; i < TM; ++i) {
    int m = bm + ty * TM + i;
    uint32_t* row = (uint32_t*)(Uk + (size_t)m * DD + bn + tx * TN);
#pragma unroll
    for (int j = 0; j < TN / 2; ++j) {
      int n = bn + tx * TN + 2 * j;
      uint32_t lo = f2bf(acc[i][2 * j] + bias[n]);
      uint32_t hi = f2bf(acc[i][2 * j + 1] + bias[n + 1]);
      row[j] = lo | (hi << 16);
    }
  }
}

// gi = ctx @ W_ih[:, :512]^T + b_ih (ld 515) ; gh = h @ W_hh^T + b_hh
__global__ __launch_bounds__(256) void gemm_gates(
    const float* __restrict__ ctx, const float* __restrict__ h,
    const float* __restrict__ W_ih, const float* __restrict__ Whh,
    const float* __restrict__ bih, const float* __restrict__ bhh,
    float* __restrict__ gi, float* __restrict__ gh) {
  if (blockIdx.z == 0)
    gemm_body<32, 64, 32, 2, 4>(ctx, DD, W_ih, DD + OO, bih, gi, 3 * DD, DD);
  else
    gemm_body<32, 64, 32, 2, 4>(h, DD, Whh, DD, bhh, gh, 3 * DD, DD);
}

// WaT_bf[d, e] = bf16(Wa[e, d])
__global__ void transp_wa_bf(const float* __restrict__ Wa,
                             unsigned short* __restrict__ WaT) {
  int idx = blockIdx.x * 256 + threadIdx.x;  // e*512+d
  int e = idx >> 9, d = idx & (DD - 1);
  WaT[(size_t)d * DD + e] = f2bf(Wa[idx]);
}

// fp32 -> bf16, 8 elems/thread
__global__ __launch_bounds__(256) void conv_e(const float* __restrict__ in,
                                              unsigned short* __restrict__ outp) {
  size_t idx = ((size_t)blockIdx.x * 256 + threadIdx.x) * 8;
  const float4* p = (const float4*)(in + idx);
  float4 a = p[0], b = p[1];
  uint4 r;
  r.x = f2bf(a.x) | ((uint32_t)f2bf(a.y) << 16);
  r.y = f2bf(a.z) | ((uint32_t)f2bf(a.w) << 16);
  r.z = f2bf(b.x) | ((uint32_t)f2bf(b.y) << 16);
  r.w = f2bf(b.z) | ((uint32_t)f2bf(b.w) << 16);
  *(uint4*)(outp + idx) = r;
}

// ---------------------------------------------------------------------------
// Weight-stationary q projection: q[b,e] = sum_d h[b,d]*WaT[d,e] + ba[e]
// grid 32 blocks (4 batches each) x 512 threads (one e-col each).
// WaT traffic/step = 32 x 0.5 MB = 16 MB (vs 128 MB fused-per-batch).
// ---------------------------------------------------------------------------
__global__ __launch_bounds__(512) void qproj_ws(
    const float* __restrict__ h, const unsigned short* __restrict__ WaT,
    const float* __restrict__ ba, float* __restrict__ q) {
  const int b0 = blockIdx.x * 4;
  const int e = threadIdx.x;
  __shared__ float sh[4][DD];
  for (int i = threadIdx.x; i < 4 * DD; i += 512)
    sh[i >> 9][i & (DD - 1)] = h[(size_t)(b0 + (i >> 9)) * DD + (i & (DD - 1))];
  __syncthreads();
  float a0 = 0.f, a1 = 0.f, a2 = 0.f, a3 = 0.f;
#pragma unroll 4
  for (int k = 0; k < DD; ++k) {
    float w = bf2f(WaT[(size_t)k * DD + e]);
    a0 += sh[0][k] * w;
    a1 += sh[1][k] * w;
    a2 += sh[2][k] * w;
    a3 += sh[3][k] * w;
  }
  const float bav = ba[e];
  q[(size_t)(b0 + 0) * DD + e] = a0 + bav;
  q[(size_t)(b0 + 1) * DD + e] = a1 + bav;
  q[(size_t)(b0 + 2) * DD + e] = a2 + bav;
  q[(size_t)(b0 + 3) * DD + e] = a3 + bav;
}

// ---------------------------------------------------------------------------
// scores[b,s] = va . tanh(q[b]+Uk[b,s]) + vb ; grid (S/64, B), 256 thr
// ---------------------------------------------------------------------------
__global__ __launch_bounds__(256) void attn_scores(
    const unsigned short* __restrict__ Uk_bf, const float* __restrict__ q,
    const float* __restrict__ va, const float* __restrict__ vb_p,
    float* __restrict__ scores) {
  const int b = blockIdx.y;
  const int s0 = blockIdx.x * 64;
  __shared__ float4 sh_q[DD / 4];
  __shared__ float4 sh_va[DD / 4];
  const int tid = threadIdx.x;
  if (tid < DD / 4) {
    sh_q[tid] = ((const float4*)(q + (size_t)b * DD))[tid];
    sh_va[tid] = ((const float4*)va)[tid];
  }
  __syncthreads();
  const float vb = vb_p[0];
  const int g = tid >> 4, l = tid & 15;
#pragma unroll
  for (int i = 0; i < 4; ++i) {
    const int s = s0 + 16 * i + g;
    const uint2* row = (const uint2*)(Uk_bf + ((size_t)b * SS + s) * DD);
    float acc = 0.f;
#pragma unroll
    for (int j = 0; j < 8; ++j) {
      uint2 u = row[l + 16 * j];
      float4 qq = sh_q[l + 16 * j];
      float4 vv = sh_va[l + 16 * j];
      float2 e0 = bfx2(u.x), e1 = bfx2(u.y);
      acc += vv.x * tanh_fast(qq.x + e0.x);
      acc += vv.y * tanh_fast(qq.y + e0.y);
      acc += vv.z * tanh_fast(qq.z + e1.x);
      acc += vv.w * tanh_fast(qq.w + e1.y);
    }
#pragma unroll
    for (int off = 8; off; off >>= 1) acc += __shfl_down(acc, off, 16);
    if (l == 0) scores[(size_t)b * SS + s] = acc + vb;
  }
}

// ---------------------------------------------------------------------------
// softmax(scores[b]) -> w ; ctx[b, d-chunk] = w . e_bf ; grid (4, B), 256 thr
// ---------------------------------------------------------------------------
__global__ __launch_bounds__(256) void attn_ctx(
    const unsigned short* __restrict__ e_bf, const float* __restrict__ scores,
    float* __restrict__ ctx, float* __restrict__ attn_out, int t) {
  const int b = blockIdx.y, dc = blockIdx.x;
  __shared__ float w[SS];
  __shared__ float red[8];
  __shared__ float2 part[4][64];
  const int tid = threadIdx.x;

  float v0 = scores[(size_t)b * SS + tid];
  float v1 = scores[(size_t)b * SS + 256 + tid];
  float m = fmaxf(v0, v1);
#pragma unroll
  for (int off = 32; off; off >>= 1) m = fmaxf(m, __shfl_xor(m, off));
  if ((tid & 63) == 0) red[tid >> 6] = m;
  __syncthreads();
  m = fmaxf(fmaxf(red[0], red[1]), fmaxf(red[2], red[3]));
  float e0 = __expf(v0 - m), e1 = __expf(v1 - m);
  float ss = e0 + e1;
#pragma unroll
  for (int off = 32; off; off >>= 1) ss += __shfl_xor(ss, off);
  __syncthreads();
  if ((tid & 63) == 0) red[tid >> 6] = ss;
  __syncthreads();
  const float inv = 1.f / (red[0] + red[1] + red[2] + red[3]);
  float w0 = e0 * inv, w1 = e1 * inv;
  w[tid] = w0;
  w[tid + 256] = w1;
  if (dc == 0) {
    float* ao = attn_out + ((size_t)b * TT + t) * SS;
    ao[tid] = w0;
    ao[tid + 256] = w1;
  }
  __syncthreads();

  // ctx over d-chunk of 128 columns; 4 s-quarters x 64 lanes (2 cols each)
  const int qrt = tid >> 6, lane = tid & 63;
  const int d0 = dc * 128;
  const uint32_t* eb = (const uint32_t*)e_bf;
  const size_t base = (size_t)b * SS * (DD / 2) + d0 / 2 + lane;
  float2 acc = {0.f, 0.f};
  const int sBeg = qrt * 128, sEnd = sBeg + 128;
  for (int s = sBeg; s < sEnd; ++s) {
    float2 e = bfx2(eb[base + (size_t)s * (DD / 2)]);
    float ws = w[s];
    acc.x += ws * e.x;
    acc.y += ws * e.y;
  }
  part[qrt][lane] = acc;
  __syncthreads();
  if (tid < 64) {
    float2 a = part[0][tid], b2 = part[1][tid], c = part[2][tid], d = part[3][tid];
    float2 r;
    r.x = a.x + b2.x + c.x + d.x;
    r.y = a.y + b2.y + c.y + d.y;
    ((float2*)(ctx + (size_t)b * DD + d0))[tid] = r;
  }
}

// ---------------------------------------------------------------------------
// GRU pointwise + output projection (x-weights read from W_ih cols 512..514).
// ---------------------------------------------------------------------------
__global__ __launch_bounds__(512) void gru_update(
    const float* __restrict__ gi, const float* __restrict__ gh,
    float* __restrict__ h,
    const float* __restrict__ W_ih, const float* __restrict__ target,
    const float* __restrict__ W_out, const float* __restrict__ b_out,
    float* __restrict__ out_d, float* __restrict__ out_hT, int t) {
  const int b = blockIdx.x;
  const int d = threadIdx.x;
  __shared__ __align__(16) float sh_hn[DD];

  float x0 = 0.f, x1 = 0.f, x2 = 0.f;
  if (t > 0) {
    const float* xp = target + ((size_t)b * TT + (t - 1)) * OO;
    x0 = xp[0]; x1 = xp[1]; x2 = xp[2];
  }
  const float* gib = gi + (size_t)b * 3 * DD;
  const float* ghb = gh + (size_t)b * 3 * DD;

  const float* w0 = W_ih + (size_t)d * (DD + OO) + DD;
  const float* w1 = W_ih + (size_t)(DD + d) * (DD + OO) + DD;
  const float* w2 = W_ih + (size_t)(2 * DD + d) * (DD + OO) + DD;
  float ir  = gib[d]          + x0 * w0[0] + x1 * w0[1] + x2 * w0[2];
  float iz  = gib[DD + d]     + x0 * w1[0] + x1 * w1[1] + x2 * w1[2];
  float in_ = gib[2 * DD + d] + x0 * w2[0] + x1 * w2[1] + x2 * w2[2];
  float hr = ghb[d], hz = ghb[DD + d], hn = ghb[2 * DD + d];

  float r = sigmoid_fast(ir + hr);
  float z = sigmoid_fast(iz + hz);
  float n = tanh_fast(in_ + r * hn);
  float hp = h[(size_t)b * DD + d];
  float hnew = (1.f - z) * n + z * hp;
  h[(size_t)b * DD + d] = hnew;
  sh_hn[d] = hnew;
  if (t == TT - 1) out_hT[(size_t)b * DD + d] = hnew;
  __syncthreads();

  const int wave = d >> 6, lane = d & 63;
  if (wave < OO) {
    const float* wrow = W_out + (size_t)wave * DD;
    float acc = 0.f;
    for (int i = lane; i < DD; i += 64) acc += sh_hn[i] * wrow[i];
#pragma unroll
    for (int off = 32; off; off >>= 1) acc += __shfl_xor(acc, off);
    if (lane == 0) out_d[((size_t)b * TT + t) * OO + wave] = acc + b_out[wave];
  }
}

// ---------------------------------------------------------------------------
extern "C" void kernel_launch(void* const* d_in, const int* in_sizes, int n_in,
                              void* d_out, int out_size, void* d_ws, size_t ws_size,
                              hipStream_t stream) {
  const float* e_all  = (const float*)d_in[0];
  const float* e_last = (const float*)d_in[1];
  const float* target = (const float*)d_in[2];
  const float* Wa     = (const float*)d_in[3];
  const float* ba     = (const float*)d_in[4];
  const float* Ua     = (const float*)d_in[5];
  const float* bu     = (const float*)d_in[6];
  const float* Va_w   = (const float*)d_in[7];
  const float* Va_b   = (const float*)d_in[8];
  const float* W_ih   = (const float*)d_in[9];
  const float* b_ih   = (const float*)d_in[10];
  const float* W_hh   = (const float*)d_in[11];
  const float* b_hh   = (const float*)d_in[12];
  const float* W_out  = (const float*)d_in[13];
  const float* b_out  = (const float*)d_in[14];

  float* out      = (float*)d_out;
  float* out_d    = out;                         // [B,T,3]
  float* out_hT   = out + (size_t)BB * TT * OO;  // [1,B,D]
  float* out_attn = out_hT + (size_t)BB * DD;    // [B,T,S]

  // Workspace: 137.36 MB — exactly the R4-validated layout (< 139.48 MB bound).
  char* wsB = (char*)d_ws;
  unsigned short* Uk_bf = (unsigned short*)wsB;                                // 67.11 MB
  unsigned short* e_bf  = (unsigned short*)(wsB + (size_t)BB * SS * DD * 2);   // 67.11 MB
  unsigned short* WaT_bf = (unsigned short*)(wsB + (size_t)BB * SS * DD * 4);  // 0.52 MB
  float* fws = (float*)(wsB + (size_t)BB * SS * DD * 4 + (size_t)DD * DD * 2);
  float* scores = fws;                            // B*S
  float* q   = scores + (size_t)BB * SS;          // B*D
  float* h   = q + (size_t)BB * DD;               // B*D
  float* ctx = h + (size_t)BB * DD;               // B*D
  float* gi  = ctx + (size_t)BB * DD;             // B*3D
  float* gh  = gi + (size_t)BB * 3 * DD;          // B*3D

  transp_wa_bf<<<(DD * DD) / 256, 256, 0, stream>>>(Wa, WaT_bf);
  conv_e<<<(BB * SS * DD) / (8 * 256), 256, 0, stream>>>(e_all, e_bf);
  gemm_uk<<<dim3(DD / 128, (BB * SS) / 128), 256, 0, stream>>>(e_all, Ua, bu, Uk_bf);
  hipMemcpyAsync(h, e_last, (size_t)BB * DD * sizeof(float),
                 hipMemcpyDeviceToDevice, stream);
  qproj_ws<<<BB / 4, 512, 0, stream>>>(h, WaT_bf, ba, q);

  for (int t = 0; t < TT; ++t) {
    attn_scores<<<dim3(SS / 64, BB), 256, 0, stream>>>(Uk_bf, q, Va_w, Va_b, scores);
    attn_ctx<<<dim3(4, BB), 256, 0, stream>>>(e_bf, scores, ctx, out_attn, t);
    gemm_gates<<<dim3((3 * DD) / 64, BB / 32, 2), 256, 0, stream>>>(
        ctx, h, W_ih, W_hh, b_ih, b_hh, gi, gh);
    gru_update<<<BB, 512, 0, stream>>>(gi, gh, h, W_ih, target, W_out, b_out,
                                       out_d, out_hT, t);
    qproj_ws<<<BB / 4, 512, 0, stream>>>(h, WaT_bf, ba, q);
  }
}

// Round 6
// 6919.777 us; speedup vs baseline: 2.6024x; 1.0153x over previous
//
#include <hip/hip_runtime.h>
#include <cstdint>

constexpr int BB = 128;   // batch
constexpr int SS = 512;   // source length
constexpr int DD = 512;   // hidden dim
constexpr int TT = 64;    // decode steps
constexpr int OO = 3;     // output dim

__device__ __forceinline__ float tanh_fast(float x) {
  float e = __expf(2.0f * x);
  return 1.0f - 2.0f / (e + 1.0f);
}
__device__ __forceinline__ float sigmoid_fast(float x) {
  return 1.0f / (1.0f + __expf(-x));
}
__device__ __forceinline__ unsigned short f2bf(float f) {
  uint32_t u = __float_as_uint(f);
  uint32_t r = (u + 0x7FFFu + ((u >> 16) & 1u)) >> 16;  // RNE
  return (unsigned short)r;
}
__device__ __forceinline__ float2 bfx2(uint32_t u) {
  float2 r;
  r.x = __uint_as_float(u << 16);
  r.y = __uint_as_float(u & 0xFFFF0000u);
  return r;
}

// ---------------------------------------------------------------------------
// Generic tiled fp32 GEMM body: C[m,n] = sum_k A[m,k] * Bw[n,k] + bias[n]
// ---------------------------------------------------------------------------
template<int BM, int BN, int BK, int TM, int TN>
__device__ __forceinline__ void gemm_body(
    const float* __restrict__ A, int lda,
    const float* __restrict__ Bw, int ldb,
    const float* __restrict__ bias,
    float* __restrict__ C, int ldc, int K) {
  constexpr int TX = BN / TN, TY = BM / TM;
  static_assert(TX * TY == 256, "tile/thread mismatch");
  __shared__ float As[BK][BM + 4];
  __shared__ float Bs[BK][BN + 4];
  const int tid = threadIdx.x;
  const int bm = blockIdx.y * BM, bn = blockIdx.x * BN;
  const int tx = tid % TX, ty = tid / TX;
  float acc[TM][TN];
#pragma unroll
  for (int i = 0; i < TM; ++i)
#pragma unroll
    for (int j = 0; j < TN; ++j) acc[i][j] = 0.f;

  for (int k0 = 0; k0 < K; k0 += BK) {
#pragma unroll
    for (int i = 0; i < BM * BK / 256; ++i) {
      int idx = tid + i * 256;
      int m = idx / BK, k = idx % BK;
      As[k][m] = A[(size_t)(bm + m) * lda + k0 + k];
    }
#pragma unroll
    for (int i = 0; i < BN * BK / 256; ++i) {
      int idx = tid + i * 256;
      int n = idx / BK, k = idx % BK;
      Bs[k][n] = Bw[(size_t)(bn + n) * ldb + k0 + k];
    }
    __syncthreads();
#pragma unroll
    for (int k = 0; k < BK; ++k) {
      float ra[TM], rb[TN];
#pragma unroll
      for (int i = 0; i < TM; ++i) ra[i] = As[k][ty * TM + i];
#pragma unroll
      for (int j = 0; j < TN; ++j) rb[j] = Bs[k][tx * TN + j];
#pragma unroll
      for (int i = 0; i < TM; ++i)
#pragma unroll
        for (int j = 0; j < TN; ++j) acc[i][j] += ra[i] * rb[j];
    }
    __syncthreads();
  }
#pragma unroll
  for (int i = 0; i < TM; ++i) {
    int m = bm + ty * TM + i;
#pragma unroll
    for (int j = 0; j < TN; ++j) {
      int n = bn + tx * TN + j;
      C[(size_t)m * ldc + n] = acc[i][j] + bias[n];
    }
  }
}

// Uk = e_all(view [B*S, D]) @ Ua^T + bu -> bf16 [B*S, D]
__global__ __launch_bounds__(256) void gemm_uk(
    const float* __restrict__ A, const float* __restrict__ Bw,
    const float* __restrict__ bias, unsigned short* __restrict__ Uk) {
  constexpr int BM = 128, BN = 128, BK = 16, TM = 8, TN = 8, TX = 16;
  __shared__ float As[BK][BM + 4];
  __shared__ float Bs[BK][BN + 4];
  const int tid = threadIdx.x;
  const int bm = blockIdx.y * BM, bn = blockIdx.x * BN;
  const int tx = tid % TX, ty = tid / TX;
  float acc[TM][TN];
#pragma unroll
  for (int i = 0; i < TM; ++i)
#pragma unroll
    for (int j = 0; j < TN; ++j) acc[i][j] = 0.f;

  for (int k0 = 0; k0 < DD; k0 += BK) {
#pragma unroll
    for (int i = 0; i < BM * BK / 256; ++i) {
      int idx = tid + i * 256;
      int m = idx / BK, k = idx % BK;
      As[k][m] = A[(size_t)(bm + m) * DD + k0 + k];
    }
#pragma unroll
    for (int i = 0; i < BN * BK / 256; ++i) {
      int idx = tid + i * 256;
      int n = idx / BK, k = idx % BK;
      Bs[k][n] = Bw[(size_t)(bn + n) * DD + k0 + k];
    }
    __syncthreads();
#pragma unroll
    for (int k = 0; k < BK; ++k) {
      float ra[TM], rb[TN];
#pragma unroll
      for (int i = 0; i < TM; ++i) ra[i] = As[k][ty * TM + i];
#pragma unroll
      for (int j = 0; j < TN; ++j) rb[j] = Bs[k][tx * TN + j];
#pragma unroll
      for (int i = 0; i < TM; ++i)
#pragma unroll
        for (int j = 0; j < TN; ++j) acc[i][j] += ra[i] * rb[j];
    }
    __syncthreads();
  }
#pragma unroll
  for (int i = 0; i < TM; ++i) {
    int m = bm + ty * TM + i;
    uint32_t* row = (uint32_t*)(Uk + (size_t)m * DD + bn + tx * TN);
#pragma unroll
    for (int j = 0; j < TN / 2; ++j) {
      int n = bn + tx * TN + 2 * j;
      uint32_t lo = f2bf(acc[i][2 * j] + bias[n]);
      uint32_t hi = f2bf(acc[i][2 * j + 1] + bias[n + 1]);
      row[j] = lo | (hi << 16);
    }
  }
}

// fp32 -> bf16, 8 elems/thread
__global__ __launch_bounds__(256) void conv_e(const float* __restrict__ in,
                                              unsigned short* __restrict__ outp) {
  size_t idx = ((size_t)blockIdx.x * 256 + threadIdx.x) * 8;
  const float4* p = (const float4*)(in + idx);
  float4 a = p[0], b = p[1];
  uint4 r;
  r.x = f2bf(a.x) | ((uint32_t)f2bf(a.y) << 16);
  r.y = f2bf(a.z) | ((uint32_t)f2bf(a.w) << 16);
  r.z = f2bf(b.x) | ((uint32_t)f2bf(b.y) << 16);
  r.w = f2bf(b.z) | ((uint32_t)f2bf(b.w) << 16);
  *(uint4*)(outp + idx) = r;
}

// Wcat_bf packed as uint32[512 k][1024 col-pairs]:
// col j<512 -> Wa[j][k] (q proj) ; col j>=512 -> W_hh[j-512][k] (gh)
__global__ void prep_wcat(const float* __restrict__ Wa,
                          const float* __restrict__ Whh,
                          uint32_t* __restrict__ Wcat) {
  int idx = blockIdx.x * 256 + threadIdx.x;  // 512*1024
  int k = idx >> 10, j2 = idx & 1023;
  int j0 = 2 * j2;
  float v0 = (j0 < DD) ? Wa[(size_t)j0 * DD + k] : Whh[(size_t)(j0 - DD) * DD + k];
  float v1 = (j0 + 1 < DD) ? Wa[(size_t)(j0 + 1) * DD + k]
                           : Whh[(size_t)(j0 + 1 - DD) * DD + k];
  Wcat[idx] = (uint32_t)f2bf(v0) | ((uint32_t)f2bf(v1) << 16);
}

__global__ void prep_bcat(const float* __restrict__ ba,
                          const float* __restrict__ bhh,
                          float* __restrict__ bcat) {
  int j = blockIdx.x * 256 + threadIdx.x;  // 2048
  bcat[j] = (j < DD) ? ba[j] : bhh[j - DD];
}

// ---------------------------------------------------------------------------
// [q | gh] = hn @ Wcat + bcat   (shared device body; hn in LDS, 1024 threads)
// ---------------------------------------------------------------------------
__device__ __forceinline__ void qgh_gemm(
    const float* __restrict__ hn_sh, const uint32_t* __restrict__ Wcat,
    const float* __restrict__ bcat, float* __restrict__ q,
    float* __restrict__ gh, int b, int tid) {
  float2 acc = {0.f, 0.f};
#pragma unroll 8
  for (int k = 0; k < DD; ++k) {
    float2 wv = bfx2(Wcat[(size_t)k * 1024 + tid]);
    float hv = hn_sh[k];
    acc.x += hv * wv.x;
    acc.y += hv * wv.y;
  }
  const int j0 = 2 * tid;
  acc.x += bcat[j0];
  acc.y += bcat[j0 + 1];
  if (j0 < DD) {
    q[(size_t)b * DD + j0] = acc.x;
    q[(size_t)b * DD + j0 + 1] = acc.y;
  } else {
    gh[(size_t)b * 3 * DD + j0 - DD] = acc.x;
    gh[(size_t)b * 3 * DD + j0 + 1 - DD] = acc.y;
  }
}

// init: h = e_last ; [q, gh] = h @ Wcat + bcat
__global__ __launch_bounds__(1024) void qgh_init(
    const float* __restrict__ e_last, const uint32_t* __restrict__ Wcat,
    const float* __restrict__ bcat, float* __restrict__ h,
    float* __restrict__ q, float* __restrict__ gh) {
  const int b = blockIdx.x, tid = threadIdx.x;
  __shared__ float hn[DD];
  if (tid < DD) {
    float v = e_last[(size_t)b * DD + tid];
    hn[tid] = v;
    h[(size_t)b * DD + tid] = v;
  }
  __syncthreads();
  qgh_gemm(hn, Wcat, bcat, q, gh, b, tid);
}

// ---------------------------------------------------------------------------
// Fused attention: scores + softmax + ctx + attn_out. 128 blocks x 1024 thr.
// ---------------------------------------------------------------------------
__global__ __launch_bounds__(1024) void attn_fused(
    const unsigned short* __restrict__ Uk_bf,
    const unsigned short* __restrict__ e_bf,
    const float* __restrict__ q, const float* __restrict__ va,
    const float* __restrict__ vb_p,
    float* __restrict__ ctx, float* __restrict__ attn_out, int t) {
  const int b = blockIdx.x, tid = threadIdx.x;
  __shared__ float4 shq[DD / 4];
  __shared__ float4 shva[DD / 4];
  __shared__ float w[SS];
  __shared__ float red[16];
  __shared__ float2 part[4][256];
  const int wid = tid >> 6, lane = tid & 63;

  if (tid < DD / 4) {
    shq[tid] = ((const float4*)(q + (size_t)b * DD))[tid];
    shva[tid] = ((const float4*)va)[tid];
  }
  __syncthreads();

  // ---- scores: 16 lanes per s-row, 64 rows/pass, 8 passes
  {
    const float vb = vb_p[0];
    const int g = tid >> 4, l = tid & 15;
#pragma unroll
    for (int i = 0; i < 8; ++i) {
      const int s = g + 64 * i;
      const uint2* row = (const uint2*)(Uk_bf + ((size_t)b * SS + s) * DD);
      float acc = 0.f;
#pragma unroll
      for (int j = 0; j < 8; ++j) {
        uint2 u = row[l + 16 * j];
        float4 qq = shq[l + 16 * j];
        float4 vv = shva[l + 16 * j];
        float2 e0 = bfx2(u.x), e1 = bfx2(u.y);
        acc += vv.x * tanh_fast(qq.x + e0.x);
        acc += vv.y * tanh_fast(qq.y + e0.y);
        acc += vv.z * tanh_fast(qq.z + e1.x);
        acc += vv.w * tanh_fast(qq.w + e1.y);
      }
#pragma unroll
      for (int off = 8; off; off >>= 1) acc += __shfl_down(acc, off, 16);
      if (l == 0) w[s] = acc + vb;
    }
  }
  __syncthreads();

  // ---- softmax over w[0..511]
  float v = (tid < SS) ? w[tid] : -3.4e38f;
  float m = v;
#pragma unroll
  for (int off = 32; off; off >>= 1) m = fmaxf(m, __shfl_xor(m, off));
  if (lane == 0) red[wid] = m;
  __syncthreads();
  if (tid < 16) {
    float mm = red[tid];
#pragma unroll
    for (int off = 8; off; off >>= 1) mm = fmaxf(mm, __shfl_xor(mm, off, 16));
    red[tid] = mm;
  }
  __syncthreads();
  m = red[0];
  float e_ = (tid < SS) ? __expf(v - m) : 0.f;
  float ssum = e_;
#pragma unroll
  for (int off = 32; off; off >>= 1) ssum += __shfl_xor(ssum, off);
  __syncthreads();
  if (lane == 0) red[wid] = ssum;
  __syncthreads();
  if (tid < 16) {
    float s2 = red[tid];
#pragma unroll
    for (int off = 8; off; off >>= 1) s2 += __shfl_xor(s2, off, 16);
    red[tid] = s2;
  }
  __syncthreads();
  const float inv = 1.f / red[0];
  if (tid < SS) {
    float wv = e_ * inv;
    w[tid] = wv;
    attn_out[((size_t)b * TT + t) * SS + tid] = wv;
  }
  __syncthreads();

  // ---- ctx[d-pair] = sum_s w[s] * e_bf[b,s,(2dp,2dp+1)]
  {
    const int dp = tid & 255, sg = tid >> 8;
    const uint32_t* e32 = (const uint32_t*)e_bf;
    const size_t base = (size_t)b * SS * 256 + dp;
    float2 acc = {0.f, 0.f};
    for (int s = sg * 128; s < sg * 128 + 128; ++s) {
      float2 ev = bfx2(e32[base + (size_t)s * 256]);
      float ws = w[s];
      acc.x += ws * ev.x;
      acc.y += ws * ev.y;
    }
    part[sg][dp] = acc;
    __syncthreads();
    if (tid < 256) {
      float2 r = {0.f, 0.f};
#pragma unroll
      for (int k = 0; k < 4; ++k) {
        r.x += part[k][tid].x;
        r.y += part[k][tid].y;
      }
      ((float2*)(ctx + (size_t)b * DD))[tid] = r;
    }
  }
}

// gi = ctx @ W_ih[:, :512]^T + b_ih  (ld 515), out ld 1536
__global__ __launch_bounds__(256) void gi_gemm(
    const float* __restrict__ ctx, const float* __restrict__ W_ih,
    const float* __restrict__ bih, float* __restrict__ gi) {
  gemm_body<16, 64, 32, 1, 4>(ctx, DD, W_ih, DD + OO, bih, gi, 3 * DD, DD);
}

// ---------------------------------------------------------------------------
// Fused update: GRU pointwise + out-proj + [q,gh] GEMM for next step.
// 128 blocks (one per b) x 1024 threads. All gh/h hazards intra-block.
// ---------------------------------------------------------------------------
__global__ __launch_bounds__(1024) void update_fused(
    const float* __restrict__ gi, float* __restrict__ gh,
    float* __restrict__ h,
    const float* __restrict__ W_ih, const float* __restrict__ target,
    const float* __restrict__ W_out, const float* __restrict__ b_out,
    const uint32_t* __restrict__ Wcat, const float* __restrict__ bcat,
    float* __restrict__ q,
    float* __restrict__ out_d, float* __restrict__ out_hT, int t) {
  const int b = blockIdx.x, tid = threadIdx.x;
  __shared__ float hn[DD];
  const int wid = tid >> 6, lane = tid & 63;

  if (tid < DD) {
    const int d = tid;
    float x0 = 0.f, x1 = 0.f, x2 = 0.f;
    if (t > 0) {
      const float* xp = target + ((size_t)b * TT + (t - 1)) * OO;
      x0 = xp[0]; x1 = xp[1]; x2 = xp[2];
    }
    const float* gib = gi + (size_t)b * 3 * DD;
    const float* ghb = gh + (size_t)b * 3 * DD;
    const float* w0 = W_ih + (size_t)d * (DD + OO) + DD;
    const float* w1 = W_ih + (size_t)(DD + d) * (DD + OO) + DD;
    const float* w2 = W_ih + (size_t)(2 * DD + d) * (DD + OO) + DD;
    float ir  = gib[d]          + x0 * w0[0] + x1 * w0[1] + x2 * w0[2];
    float iz  = gib[DD + d]     + x0 * w1[0] + x1 * w1[1] + x2 * w1[2];
    float in_ = gib[2 * DD + d] + x0 * w2[0] + x1 * w2[1] + x2 * w2[2];
    float r = sigmoid_fast(ir + ghb[d]);
    float z = sigmoid_fast(iz + ghb[DD + d]);
    float n = tanh_fast(in_ + r * ghb[2 * DD + d]);
    float hp = h[(size_t)b * DD + d];
    float hnew = (1.f - z) * n + z * hp;
    h[(size_t)b * DD + d] = hnew;
    hn[d] = hnew;
    if (t == TT - 1) out_hT[(size_t)b * DD + d] = hnew;
  }
  __syncthreads();

  // out[b,t,o]: waves 0..2
  if (wid < OO) {
    const float* wrow = W_out + (size_t)wid * DD;
    float acc = 0.f;
    for (int i = lane; i < DD; i += 64) acc += hn[i] * wrow[i];
#pragma unroll
    for (int off = 32; off; off >>= 1) acc += __shfl_xor(acc, off);
    if (lane == 0) out_d[((size_t)b * TT + t) * OO + wid] = acc + b_out[wid];
  }

  // [q, gh] for next step (safe: gh reads done before this, same block)
  qgh_gemm(hn, Wcat, bcat, q, gh, b, tid);
}

// ---------------------------------------------------------------------------
extern "C" void kernel_launch(void* const* d_in, const int* in_sizes, int n_in,
                              void* d_out, int out_size, void* d_ws, size_t ws_size,
                              hipStream_t stream) {
  const float* e_all  = (const float*)d_in[0];
  const float* e_last = (const float*)d_in[1];
  const float* target = (const float*)d_in[2];
  const float* Wa     = (const float*)d_in[3];
  const float* ba     = (const float*)d_in[4];
  const float* Ua     = (const float*)d_in[5];
  const float* bu     = (const float*)d_in[6];
  const float* Va_w   = (const float*)d_in[7];
  const float* Va_b   = (const float*)d_in[8];
  const float* W_ih   = (const float*)d_in[9];
  const float* b_ih   = (const float*)d_in[10];
  const float* W_hh   = (const float*)d_in[11];
  const float* b_hh   = (const float*)d_in[12];
  const float* W_out  = (const float*)d_in[13];
  const float* b_out  = (const float*)d_in[14];

  float* out      = (float*)d_out;
  float* out_d    = out;                         // [B,T,3]
  float* out_hT   = out + (size_t)BB * TT * OO;  // [1,B,D]
  float* out_attn = out_hT + (size_t)BB * DD;    // [B,T,S]

  // Workspace: 138,682,368 B < 139,479,040 B (R1-proven ws_size lower bound).
  char* wsB = (char*)d_ws;
  unsigned short* Uk_bf = (unsigned short*)wsB;                               // 67.11 MB
  unsigned short* e_bf  = (unsigned short*)(wsB + (size_t)BB * SS * DD * 2);  // 67.11 MB
  uint32_t* Wcat = (uint32_t*)(wsB + (size_t)BB * SS * DD * 4);               // 2.10 MB
  float* fws = (float*)(wsB + (size_t)BB * SS * DD * 4 + (size_t)DD * 2048 * 2);
  float* bcat = fws;                              // 2048
  float* q    = bcat + 2048;                      // B*D
  float* h    = q + (size_t)BB * DD;              // B*D
  float* ctx  = h + (size_t)BB * DD;              // B*D
  float* gi   = ctx + (size_t)BB * DD;            // B*3D
  float* gh   = gi + (size_t)BB * 3 * DD;         // B*3D

  prep_wcat<<<(DD * 1024) / 256, 256, 0, stream>>>(Wa, W_hh, Wcat);
  prep_bcat<<<2048 / 256, 256, 0, stream>>>(ba, b_hh, bcat);
  conv_e<<<(BB * SS * DD) / (8 * 256), 256, 0, stream>>>(e_all, e_bf);
  gemm_uk<<<dim3(DD / 128, (BB * SS) / 128), 256, 0, stream>>>(e_all, Ua, bu, Uk_bf);
  qgh_init<<<BB, 1024, 0, stream>>>(e_last, Wcat, bcat, h, q, gh);

  for (int t = 0; t < TT; ++t) {
    attn_fused<<<BB, 1024, 0, stream>>>(Uk_bf, e_bf, q, Va_w, Va_b,
                                        ctx, out_attn, t);
    gi_gemm<<<dim3(3 * DD / 64, BB / 16), 256, 0, stream>>>(ctx, W_ih, b_ih, gi);
    update_fused<<<BB, 1024, 0, stream>>>(gi, gh, h, W_ih, target, W_out, b_out,
                                          Wcat, bcat, q, out_d, out_hT, t);
  }
}

// Round 7
// 5621.139 us; speedup vs baseline: 3.2036x; 1.2310x over previous
//
#include <hip/hip_runtime.h>
#include <cstdint>

constexpr int BB = 128;   // batch
constexpr int SS = 512;   // source length
constexpr int DD = 512;   // hidden dim
constexpr int TT = 64;    // decode steps
constexpr int OO = 3;     // output dim

typedef __attribute__((ext_vector_type(8))) short bf16x8;
typedef __attribute__((ext_vector_type(4))) float f32x4;

__device__ __forceinline__ float tanh_fast(float x) {
  float e = __expf(2.0f * x);
  return 1.0f - 2.0f / (e + 1.0f);
}
__device__ __forceinline__ float sigmoid_fast(float x) {
  return 1.0f / (1.0f + __expf(-x));
}
__device__ __forceinline__ unsigned short f2bf(float f) {
  uint32_t u = __float_as_uint(f);
  uint32_t r = (u + 0x7FFFu + ((u >> 16) & 1u)) >> 16;  // RNE
  return (unsigned short)r;
}
__device__ __forceinline__ float2 bfx2(uint32_t u) {
  float2 r;
  r.x = __uint_as_float(u << 16);
  r.y = __uint_as_float(u & 0xFFFF0000u);
  return r;
}

// ---------------------------------------------------------------------------
// Generic tiled fp32 GEMM body (used for gi): C = A @ Bw^T + bias
// ---------------------------------------------------------------------------
template<int BM, int BN, int BK, int TM, int TN>
__device__ __forceinline__ void gemm_body(
    const float* __restrict__ A, int lda,
    const float* __restrict__ Bw, int ldb,
    const float* __restrict__ bias,
    float* __restrict__ C, int ldc, int K) {
  constexpr int TX = BN / TN, TY = BM / TM;
  static_assert(TX * TY == 256, "tile/thread mismatch");
  __shared__ float As[BK][BM + 4];
  __shared__ float Bs[BK][BN + 4];
  const int tid = threadIdx.x;
  const int bm = blockIdx.y * BM, bn = blockIdx.x * BN;
  const int tx = tid % TX, ty = tid / TX;
  float acc[TM][TN];
#pragma unroll
  for (int i = 0; i < TM; ++i)
#pragma unroll
    for (int j = 0; j < TN; ++j) acc[i][j] = 0.f;

  for (int k0 = 0; k0 < K; k0 += BK) {
#pragma unroll
    for (int i = 0; i < BM * BK / 256; ++i) {
      int idx = tid + i * 256;
      int m = idx / BK, k = idx % BK;
      As[k][m] = A[(size_t)(bm + m) * lda + k0 + k];
    }
#pragma unroll
    for (int i = 0; i < BN * BK / 256; ++i) {
      int idx = tid + i * 256;
      int n = idx / BK, k = idx % BK;
      Bs[k][n] = Bw[(size_t)(bn + n) * ldb + k0 + k];
    }
    __syncthreads();
#pragma unroll
    for (int k = 0; k < BK; ++k) {
      float ra[TM], rb[TN];
#pragma unroll
      for (int i = 0; i < TM; ++i) ra[i] = As[k][ty * TM + i];
#pragma unroll
      for (int j = 0; j < TN; ++j) rb[j] = Bs[k][tx * TN + j];
#pragma unroll
      for (int i = 0; i < TM; ++i)
#pragma unroll
        for (int j = 0; j < TN; ++j) acc[i][j] += ra[i] * rb[j];
    }
    __syncthreads();
  }
#pragma unroll
  for (int i = 0; i < TM; ++i) {
    int m = bm + ty * TM + i;
#pragma unroll
    for (int j = 0; j < TN; ++j) {
      int n = bn + tx * TN + j;
      C[(size_t)m * ldc + n] = acc[i][j] + bias[n];
    }
  }
}

// ---------------------------------------------------------------------------
// MFMA bf16 GEMM: Uk = e_bf [65536x512] @ Ua_bf^T [512x512] + bu -> bf16
// 128x128 block tile, 4 waves each 64x64 (4x4 of 16x16x32 MFMA).
// LDS pitch 40 shorts (80 B): 16-B aligned rows, 2-way-max bank aliasing.
// ---------------------------------------------------------------------------
__global__ __launch_bounds__(256) void gemm_uk_mfma(
    const unsigned short* __restrict__ A, const unsigned short* __restrict__ Bw,
    const float* __restrict__ bias, unsigned short* __restrict__ Uk) {
  __shared__ unsigned short Asb[128 * 40];
  __shared__ unsigned short Bsb[128 * 40];
  const int tid = threadIdx.x;
  const int m0 = blockIdx.y * 128, n0 = blockIdx.x * 128;
  const int w = tid >> 6, l = tid & 63;
  const int wr = w >> 1, wc = w & 1;
  const int lm = l & 15, kg = l >> 4;

  f32x4 acc[4][4] = {};

  for (int kc = 0; kc < 512; kc += 32) {
    // stage 128x32 A and B tiles: 512 uint4 each, 2 per thread
    uint4 av[2], bv[2];
#pragma unroll
    for (int p = 0; p < 2; ++p) {
      int u = tid + p * 256;
      int r = u >> 2, ko = (u & 3) * 8;
      av[p] = *(const uint4*)(A + (size_t)(m0 + r) * 512 + kc + ko);
      bv[p] = *(const uint4*)(Bw + (size_t)(n0 + r) * 512 + kc + ko);
    }
    __syncthreads();
#pragma unroll
    for (int p = 0; p < 2; ++p) {
      int u = tid + p * 256;
      int r = u >> 2, ko = (u & 3) * 8;
      *(uint4*)&Asb[r * 40 + ko] = av[p];
      *(uint4*)&Bsb[r * 40 + ko] = bv[p];
    }
    __syncthreads();
    bf16x8 af[4], bfr[4];
#pragma unroll
    for (int i = 0; i < 4; ++i) {
      af[i]  = *(const bf16x8*)&Asb[(wr * 64 + i * 16 + lm) * 40 + kg * 8];
      bfr[i] = *(const bf16x8*)&Bsb[(wc * 64 + i * 16 + lm) * 40 + kg * 8];
    }
#pragma unroll
    for (int i = 0; i < 4; ++i)
#pragma unroll
      for (int j = 0; j < 4; ++j)
        acc[i][j] = __builtin_amdgcn_mfma_f32_16x16x32_bf16(af[i], bfr[j],
                                                            acc[i][j], 0, 0, 0);
  }

  // epilogue: C/D layout col=lane&15, row=(lane>>4)*4+reg  [verified m89/m91]
  const int row_base = m0 + wr * 64;
  const int col_base = n0 + wc * 64;
#pragma unroll
  for (int j = 0; j < 4; ++j) {
    const int col = col_base + j * 16 + lm;
    const float bu = bias[col];
#pragma unroll
    for (int i = 0; i < 4; ++i) {
      const int r0 = row_base + i * 16 + kg * 4;
#pragma unroll
      for (int rr = 0; rr < 4; ++rr)
        Uk[(size_t)(r0 + rr) * 512 + col] = f2bf(acc[i][j][rr] + bu);
    }
  }
}

// fp32 -> bf16, 8 elems/thread (used for e_all and Ua)
__global__ __launch_bounds__(256) void conv_bf(const float* __restrict__ in,
                                               unsigned short* __restrict__ outp) {
  size_t idx = ((size_t)blockIdx.x * 256 + threadIdx.x) * 8;
  const float4* p = (const float4*)(in + idx);
  float4 a = p[0], b = p[1];
  uint4 r;
  r.x = f2bf(a.x) | ((uint32_t)f2bf(a.y) << 16);
  r.y = f2bf(a.z) | ((uint32_t)f2bf(a.w) << 16);
  r.z = f2bf(b.x) | ((uint32_t)f2bf(b.y) << 16);
  r.w = f2bf(b.z) | ((uint32_t)f2bf(b.w) << 16);
  *(uint4*)(outp + idx) = r;
}

// Wcat packed uint32[512 k][1024 col-pairs]: j<512 -> Wa[j][k], else W_hh[j-512][k]
__global__ void prep_wcat(const float* __restrict__ Wa,
                          const float* __restrict__ Whh,
                          uint32_t* __restrict__ Wcat) {
  int idx = blockIdx.x * 256 + threadIdx.x;  // 512*1024
  int k = idx >> 10, j2 = idx & 1023;
  int j0 = 2 * j2;
  float v0 = (j0 < DD) ? Wa[(size_t)j0 * DD + k] : Whh[(size_t)(j0 - DD) * DD + k];
  float v1 = (j0 + 1 < DD) ? Wa[(size_t)(j0 + 1) * DD + k]
                           : Whh[(size_t)(j0 + 1 - DD) * DD + k];
  Wcat[idx] = (uint32_t)f2bf(v0) | ((uint32_t)f2bf(v1) << 16);
}

__global__ void prep_bcat(const float* __restrict__ ba,
                          const float* __restrict__ bhh,
                          float* __restrict__ bcat) {
  int j = blockIdx.x * 256 + threadIdx.x;  // 2048
  bcat[j] = (j < DD) ? ba[j] : bhh[j - DD];
}

// ---------------------------------------------------------------------------
// [q | gh] = hn @ Wcat + bcat   (hn in LDS, 1024 threads, 2 cols/thread)
// ---------------------------------------------------------------------------
__device__ __forceinline__ void qgh_gemm(
    const float* __restrict__ hn_sh, const uint32_t* __restrict__ Wcat,
    const float* __restrict__ bcat, float* __restrict__ q,
    float* __restrict__ gh, int b, int tid) {
  float2 acc = {0.f, 0.f};
#pragma unroll 8
  for (int k = 0; k < DD; ++k) {
    float2 wv = bfx2(Wcat[(size_t)k * 1024 + tid]);
    float hv = hn_sh[k];
    acc.x += hv * wv.x;
    acc.y += hv * wv.y;
  }
  const int j0 = 2 * tid;
  acc.x += bcat[j0];
  acc.y += bcat[j0 + 1];
  if (j0 < DD) {
    q[(size_t)b * DD + j0] = acc.x;
    q[(size_t)b * DD + j0 + 1] = acc.y;
  } else {
    gh[(size_t)b * 3 * DD + j0 - DD] = acc.x;
    gh[(size_t)b * 3 * DD + j0 + 1 - DD] = acc.y;
  }
}

// init: h = e_last ; [q, gh] = h @ Wcat + bcat
__global__ __launch_bounds__(1024) void qgh_init(
    const float* __restrict__ e_last, const uint32_t* __restrict__ Wcat,
    const float* __restrict__ bcat, float* __restrict__ h,
    float* __restrict__ q, float* __restrict__ gh) {
  const int b = blockIdx.x, tid = threadIdx.x;
  __shared__ float hn[DD];
  if (tid < DD) {
    float v = e_last[(size_t)b * DD + tid];
    hn[tid] = v;
    h[(size_t)b * DD + tid] = v;
  }
  __syncthreads();
  qgh_gemm(hn, Wcat, bcat, q, gh, b, tid);
}

// ---------------------------------------------------------------------------
// scores[b,s] = va . tanh(q[b]+Uk[b,s]) + vb ; grid (8, B) x 256 thr.
// 16-B (uint4) Uk loads: 4 independent loads per (row, lane).
// ---------------------------------------------------------------------------
__global__ __launch_bounds__(256) void attn_scores(
    const unsigned short* __restrict__ Uk_bf, const float* __restrict__ q,
    const float* __restrict__ va, const float* __restrict__ vb_p,
    float* __restrict__ scores) {
  const int b = blockIdx.y;
  const int s0 = blockIdx.x * 64;
  __shared__ float4 shq[DD / 4];
  __shared__ float4 shva[DD / 4];
  const int tid = threadIdx.x;
  if (tid < DD / 4) {
    shq[tid] = ((const float4*)(q + (size_t)b * DD))[tid];
    shva[tid] = ((const float4*)va)[tid];
  }
  __syncthreads();
  const float vb = vb_p[0];
  const int g = tid >> 4, l = tid & 15;
#pragma unroll
  for (int i = 0; i < 4; ++i) {
    const int s = s0 + 16 * i + g;
    const uint4* row = (const uint4*)(Uk_bf + ((size_t)b * SS + s) * DD);
    float acc = 0.f;
#pragma unroll
    for (int jj = 0; jj < 4; ++jj) {
      const int slot = l + 16 * jj;       // uint4 index 0..63
      uint4 u = row[slot];
      float4 q0 = shq[slot * 2], q1 = shq[slot * 2 + 1];
      float4 v0 = shva[slot * 2], v1 = shva[slot * 2 + 1];
      float2 e0 = bfx2(u.x), e1 = bfx2(u.y), e2 = bfx2(u.z), e3 = bfx2(u.w);
      acc += v0.x * tanh_fast(q0.x + e0.x);
      acc += v0.y * tanh_fast(q0.y + e0.y);
      acc += v0.z * tanh_fast(q0.z + e1.x);
      acc += v0.w * tanh_fast(q0.w + e1.y);
      acc += v1.x * tanh_fast(q1.x + e2.x);
      acc += v1.y * tanh_fast(q1.y + e2.y);
      acc += v1.z * tanh_fast(q1.z + e3.x);
      acc += v1.w * tanh_fast(q1.w + e3.y);
    }
#pragma unroll
    for (int off = 8; off; off >>= 1) acc += __shfl_down(acc, off, 16);
    if (l == 0) scores[(size_t)b * SS + s] = acc + vb;
  }
}

// ---------------------------------------------------------------------------
// softmax(scores[b]) -> w ; ctx[b, d-chunk of 128] = w . e_bf ; grid (4, B).
// 16-B (uint4) e_bf loads; 16 s-groups x 16 col-slots of 8.
// ---------------------------------------------------------------------------
__global__ __launch_bounds__(256) void attn_ctx(
    const unsigned short* __restrict__ e_bf, const float* __restrict__ scores,
    float* __restrict__ ctx, float* __restrict__ attn_out, int t) {
  const int b = blockIdx.y, dc = blockIdx.x;
  __shared__ float w[SS];
  __shared__ float red[8];
  __shared__ float part[16][132];  // [sg][sl*8+c], pitch 132
  const int tid = threadIdx.x;

  float v0 = scores[(size_t)b * SS + tid];
  float v1 = scores[(size_t)b * SS + 256 + tid];
  float m = fmaxf(v0, v1);
#pragma unroll
  for (int off = 32; off; off >>= 1) m = fmaxf(m, __shfl_xor(m, off));
  if ((tid & 63) == 0) red[tid >> 6] = m;
  __syncthreads();
  m = fmaxf(fmaxf(red[0], red[1]), fmaxf(red[2], red[3]));
  float e0 = __expf(v0 - m), e1 = __expf(v1 - m);
  float ss = e0 + e1;
#pragma unroll
  for (int off = 32; off; off >>= 1) ss += __shfl_xor(ss, off);
  __syncthreads();
  if ((tid & 63) == 0) red[tid >> 6] = ss;
  __syncthreads();
  const float inv = 1.f / (red[0] + red[1] + red[2] + red[3]);
  float w0 = e0 * inv, w1 = e1 * inv;
  w[tid] = w0;
  w[tid + 256] = w1;
  if (dc == 0) {
    float* ao = attn_out + ((size_t)b * TT + t) * SS;
    ao[tid] = w0;
    ao[tid + 256] = w1;
  }
  __syncthreads();

  // ctx: thread (sg=tid>>4, sl=tid&15): 32 s-rows, 8 cols at dc*128+sl*8
  {
    const int sl = tid & 15, sg = tid >> 4;
    const unsigned short* eb = e_bf + (size_t)b * SS * DD + dc * 128 + sl * 8;
    float a0 = 0.f, a1 = 0.f, a2 = 0.f, a3 = 0.f;
    float a4 = 0.f, a5 = 0.f, a6 = 0.f, a7 = 0.f;
    for (int s = sg * 32; s < sg * 32 + 32; ++s) {
      uint4 u = *(const uint4*)(eb + (size_t)s * DD);
      float ws = w[s];
      float2 p0 = bfx2(u.x), p1 = bfx2(u.y), p2 = bfx2(u.z), p3 = bfx2(u.w);
      a0 += ws * p0.x; a1 += ws * p0.y;
      a2 += ws * p1.x; a3 += ws * p1.y;
      a4 += ws * p2.x; a5 += ws * p2.y;
      a6 += ws * p3.x; a7 += ws * p3.y;
    }
    float* pr = &part[sg][sl * 8];
    pr[0] = a0; pr[1] = a1; pr[2] = a2; pr[3] = a3;
    pr[4] = a4; pr[5] = a5; pr[6] = a6; pr[7] = a7;
  }
  __syncthreads();
  if (tid < 128) {
    const int sl = tid >> 3, c = tid & 7;
    float r = 0.f;
#pragma unroll
    for (int sg = 0; sg < 16; ++sg) r += part[sg][sl * 8 + c];
    ctx[(size_t)b * DD + dc * 128 + sl * 8 + c] = r;
  }
}

// gi = ctx @ W_ih[:, :512]^T + b_ih  (ld 515), out ld 1536
__global__ __launch_bounds__(256) void gi_gemm(
    const float* __restrict__ ctx, const float* __restrict__ W_ih,
    const float* __restrict__ bih, float* __restrict__ gi) {
  gemm_body<16, 64, 32, 1, 4>(ctx, DD, W_ih, DD + OO, bih, gi, 3 * DD, DD);
}

// ---------------------------------------------------------------------------
// Fused update: GRU pointwise + out-proj + [q,gh] GEMM for next step.
// ---------------------------------------------------------------------------
__global__ __launch_bounds__(1024) void update_fused(
    const float* __restrict__ gi, float* __restrict__ gh,
    float* __restrict__ h,
    const float* __restrict__ W_ih, const float* __restrict__ target,
    const float* __restrict__ W_out, const float* __restrict__ b_out,
    const uint32_t* __restrict__ Wcat, const float* __restrict__ bcat,
    float* __restrict__ q,
    float* __restrict__ out_d, float* __restrict__ out_hT, int t) {
  const int b = blockIdx.x, tid = threadIdx.x;
  __shared__ float hn[DD];
  const int wid = tid >> 6, lane = tid & 63;

  if (tid < DD) {
    const int d = tid;
    float x0 = 0.f, x1 = 0.f, x2 = 0.f;
    if (t > 0) {
      const float* xp = target + ((size_t)b * TT + (t - 1)) * OO;
      x0 = xp[0]; x1 = xp[1]; x2 = xp[2];
    }
    const float* gib = gi + (size_t)b * 3 * DD;
    const float* ghb = gh + (size_t)b * 3 * DD;
    const float* w0 = W_ih + (size_t)d * (DD + OO) + DD;
    const float* w1 = W_ih + (size_t)(DD + d) * (DD + OO) + DD;
    const float* w2 = W_ih + (size_t)(2 * DD + d) * (DD + OO) + DD;
    float ir  = gib[d]          + x0 * w0[0] + x1 * w0[1] + x2 * w0[2];
    float iz  = gib[DD + d]     + x0 * w1[0] + x1 * w1[1] + x2 * w1[2];
    float in_ = gib[2 * DD + d] + x0 * w2[0] + x1 * w2[1] + x2 * w2[2];
    float r = sigmoid_fast(ir + ghb[d]);
    float z = sigmoid_fast(iz + ghb[DD + d]);
    float n = tanh_fast(in_ + r * ghb[2 * DD + d]);
    float hp = h[(size_t)b * DD + d];
    float hnew = (1.f - z) * n + z * hp;
    h[(size_t)b * DD + d] = hnew;
    hn[d] = hnew;
    if (t == TT - 1) out_hT[(size_t)b * DD + d] = hnew;
  }
  __syncthreads();

  if (wid < OO) {
    const float* wrow = W_out + (size_t)wid * DD;
    float acc = 0.f;
    for (int i = lane; i < DD; i += 64) acc += hn[i] * wrow[i];
#pragma unroll
    for (int off = 32; off; off >>= 1) acc += __shfl_xor(acc, off);
    if (lane == 0) out_d[((size_t)b * TT + t) * OO + wid] = acc + b_out[wid];
  }

  qgh_gemm(hn, Wcat, bcat, q, gh, b, tid);
}

// ---------------------------------------------------------------------------
extern "C" void kernel_launch(void* const* d_in, const int* in_sizes, int n_in,
                              void* d_out, int out_size, void* d_ws, size_t ws_size,
                              hipStream_t stream) {
  const float* e_all  = (const float*)d_in[0];
  const float* e_last = (const float*)d_in[1];
  const float* target = (const float*)d_in[2];
  const float* Wa     = (const float*)d_in[3];
  const float* ba     = (const float*)d_in[4];
  const float* Ua     = (const float*)d_in[5];
  const float* bu     = (const float*)d_in[6];
  const float* Va_w   = (const float*)d_in[7];
  const float* Va_b   = (const float*)d_in[8];
  const float* W_ih   = (const float*)d_in[9];
  const float* b_ih   = (const float*)d_in[10];
  const float* W_hh   = (const float*)d_in[11];
  const float* b_hh   = (const float*)d_in[12];
  const float* W_out  = (const float*)d_in[13];
  const float* b_out  = (const float*)d_in[14];

  float* out      = (float*)d_out;
  float* out_d    = out;                         // [B,T,3]
  float* out_hT   = out + (size_t)BB * TT * OO;  // [1,B,D]
  float* out_attn = out_hT + (size_t)BB * DD;    // [B,T,S]

  // Workspace: 139,468,800 B <= 139,479,040 B (R1-proven safe size).
  char* wsB = (char*)d_ws;
  unsigned short* Uk_bf = (unsigned short*)wsB;                               // 67.11 MB
  unsigned short* e_bf  = (unsigned short*)(wsB + (size_t)BB * SS * DD * 2);  // 67.11 MB
  uint32_t* Wcat = (uint32_t*)(wsB + (size_t)BB * SS * DD * 4);               // 2.10 MB
  unsigned short* Ua_bf = (unsigned short*)(wsB + (size_t)BB * SS * DD * 4 +
                                            (size_t)DD * 2048 * 2);           // 0.52 MB
  float* fws = (float*)((char*)Ua_bf + (size_t)DD * DD * 2);
  float* bcat   = fws;                            // 2048
  float* scores = bcat + 2048;                    // B*S
  float* q    = scores + (size_t)BB * SS;         // B*D
  float* h    = q + (size_t)BB * DD;              // B*D
  float* ctx  = h + (size_t)BB * DD;              // B*D
  float* gi   = ctx + (size_t)BB * DD;            // B*3D
  float* gh   = gi + (size_t)BB * 3 * DD;         // B*3D

  prep_wcat<<<(DD * 1024) / 256, 256, 0, stream>>>(Wa, W_hh, Wcat);
  prep_bcat<<<2048 / 256, 256, 0, stream>>>(ba, b_hh, bcat);
  conv_bf<<<(BB * SS * DD) / (8 * 256), 256, 0, stream>>>(e_all, e_bf);
  conv_bf<<<(DD * DD) / (8 * 256), 256, 0, stream>>>(Ua, Ua_bf);
  gemm_uk_mfma<<<dim3(DD / 128, (BB * SS) / 128), 256, 0, stream>>>(
      e_bf, Ua_bf, bu, Uk_bf);
  qgh_init<<<BB, 1024, 0, stream>>>(e_last, Wcat, bcat, h, q, gh);

  for (int t = 0; t < TT; ++t) {
    attn_scores<<<dim3(SS / 64, BB), 256, 0, stream>>>(Uk_bf, q, Va_w, Va_b,
                                                       scores);
    attn_ctx<<<dim3(4, BB), 256, 0, stream>>>(e_bf, scores, ctx, out_attn, t);
    gi_gemm<<<dim3(3 * DD / 64, BB / 16), 256, 0, stream>>>(ctx, W_ih, b_ih, gi);
    update_fused<<<BB, 1024, 0, stream>>>(gi, gh, h, W_ih, target, W_out, b_out,
                                          Wcat, bcat, q, out_d, out_hT, t);
  }
}